// Round 10
// baseline (2333.299 us; speedup 1.0000x reference)
//
#include <hip/hip_runtime.h>

// ---------------------------------------------------------------------------
// TwoBranchFork: out = LN( concat(x@q(w_a)^T, x@q(w_b)^T) @ w_proj^T )
// Reassociated: W_eff = w_proj @ [q(w_a); q(w_b)]  (4096x4096), h = x @ W_eff^T
// Round 10: r7 + ONE-PHASE READ-AHEAD with counted lgkm (LDS drain overlaps
// MFMA). Per tile t (2 barriers/phase, stages as r7):
//  P1f[ds b23(t)(4) | stage A0(t+1)->saN | bar]
//  P1b[lgkm(4) drains b01(t),aT(t) | sb | Q1 aT*b01 -> acc[0..3][0,1] | bar]
//  P2f[ds aB(t)(8)  | stage A1(t+1)->saN | bar]
//  P2b[lgkm(8) drains b23 | sb | Q2 aT*b23 -> acc[0..3][2,3] | bar]
//  P3f[stage B0(t+2)->sb | vmcnt(6|4) proves B(t+1) | bar]
//  P3b[lgkm(0) drains aB | sb | ds b01(t+1)<-sbN (4) | sb |
//      Q3 aB*b23 -> acc[4..7][2,3] | bar]
//  P4f[stage B1(t+2)->sb | vmcnt(4|0) proves A(t+1) | bar]
//  P4b[sb | ds aT(t+1)<-saN (8) | sb | Q4 aB*b01 -> acc[4..7][0,1] | bar]
// lgkm ledger (issue order): b01(t)@P3b(t-1), aT(t)@P4b(t-1), b23@P1f,
//  aB@P2f, b01(t+1)@P3b, aT(t+1)@P4b. P1b lgkm(4): 16 outstanding -> drains
//  b01+aT, leaves b23. P2b lgkm(8): 12 -> drains b23. P3b lgkm(0): drains aB.
//  Q4 operands already drained -> no wait; aT(t+1)/b01(t+1) drain DURING
//  Q4/Q1 MFMA (the overlap this round buys).
// vm ledger (steady): entering t: B(t+1) 4 in flight. P1f+2, P2f+2 (A(t+1)),
//  P3f+2 (B0 t+2) =10 -> vmcnt(6) drains B(t+1) [cross-wave via barrier].
//  P4f+2 =8 after drain -> vmcnt(4) drains A(t+1), leaves B(t+2) 4 ✓ steady.
//  Edges: t+2>=NT: P3f vmcnt(4), P4f vmcnt(0); t+1>=NT: no stages/waits/
//  read-aheads. WAR: B(t+2)->sb after last sb read (b23@P1f, 2 bars);
//  A(t+1)->saN after saN's last reads (aB(t-1)@P2f(t-1), 4+ bars); b01(t+1)
//  reads sbN which is not written during t; aT(t+1) reads saN post-proof.
// b01 ping-pongs between two named reg sets (both live P3b..P4b); aT single
// set (dead after Q2, rewritten P4b).
// ---------------------------------------------------------------------------

typedef unsigned int u32;
typedef unsigned short u16;
typedef __bf16 bf16x8 __attribute__((ext_vector_type(8)));
typedef float f32x4 __attribute__((ext_vector_type(4)));
typedef u16 u16x8 __attribute__((ext_vector_type(8)));

#define AS1 __attribute__((address_space(1)))
#define AS3 __attribute__((address_space(3)))

__device__ __forceinline__ u16 f2bf(float f) {
  u32 u = __float_as_uint(f);
  u32 r = (u + 0x7fffu + ((u >> 16) & 1u)) >> 16;  // RNE
  return (u16)r;
}

// fp8 e4m3fn quantize-dequantize via HW cvt (OCP format + RNE on gfx950)
__device__ __forceinline__ float q_e4m3(float v) {
  int p = __builtin_amdgcn_cvt_pk_fp8_f32(v, v, 0, false);
  return __builtin_amdgcn_cvt_f32_fp8(p, 0);
}

__device__ __forceinline__ void gload16(const void* g, void* l) {
  __builtin_amdgcn_global_load_lds((const AS1 u32*)g, (AS3 u32*)l, 16, 0, 0);
}

// ---------------- elementwise f32 -> bf16 ----------------
__global__ __launch_bounds__(256) void k_f32_to_bf16(
    const float* __restrict__ in, u16* __restrict__ out, long n) {
  long i0 = ((long)blockIdx.x * 256 + threadIdx.x) * 8;
  long stride = (long)gridDim.x * 256 * 8;
  for (long i = i0; i < n; i += stride) {
    float4 a = *(const float4*)(in + i);
    float4 b = *(const float4*)(in + i + 4);
    u16x8 o;
    o[0] = f2bf(a.x); o[1] = f2bf(a.y); o[2] = f2bf(a.z); o[3] = f2bf(a.w);
    o[4] = f2bf(b.x); o[5] = f2bf(b.y); o[6] = f2bf(b.z); o[7] = f2bf(b.w);
    *(u16x8*)(out + i) = o;
  }
}

// ---------------- quantize (fp8 rt) + transpose into wqT ----------------
__global__ __launch_bounds__(256) void k_quant_transpose(
    const float* __restrict__ w, const float* __restrict__ s,
    u16* __restrict__ oT, int J, int Kd, int sCols, long oStride, int oColOff) {
  __shared__ u16 tile[64][72];
  int j0 = blockIdx.x * 64;
  int k0 = blockIdx.y * 64;
  float sc = s[(j0 >> 7) * sCols + (k0 >> 7)];
  int t = threadIdx.x;
  int row = t >> 2, seg = t & 3;
  const float4* src = (const float4*)(w + (long)(j0 + row) * Kd + k0 + seg * 16);
  u16* dst = &tile[row][seg * 16];
#pragma unroll
  for (int ii = 0; ii < 4; ++ii) {
    float4 v = src[ii];
    dst[ii * 4 + 0] = f2bf(q_e4m3(v.x / sc) * sc);
    dst[ii * 4 + 1] = f2bf(q_e4m3(v.y / sc) * sc);
    dst[ii * 4 + 2] = f2bf(q_e4m3(v.z / sc) * sc);
    dst[ii * 4 + 3] = f2bf(q_e4m3(v.w / sc) * sc);
  }
  __syncthreads();
  int r = t >> 2, cs = t & 3;
  u16* op = oT + (long)(k0 + r) * oStride + oColOff + j0 + cs * 16;
  u16x8 o0, o1;
#pragma unroll
  for (int ii = 0; ii < 8; ++ii) o0[ii] = tile[cs * 16 + ii][r];
#pragma unroll
  for (int ii = 0; ii < 8; ++ii) o1[ii] = tile[cs * 16 + 8 + ii][r];
  *(u16x8*)op = o0;
  *(u16x8*)(op + 8) = o1;
}

// ---------------- 256x256 8-phase bf16 bt-GEMM: C = A[M,K] * B[N,K]^T -------
template <bool OUT_BF16>
__global__ __launch_bounds__(512, 2) void k_gemm8(
    const u16* __restrict__ A, const u16* __restrict__ B, void* __restrict__ Cv,
    int M, int N, int K) {
  __shared__ u16 sAbuf[2][256 * 64];
  __shared__ u16 sBbuf[2][256 * 64];

  const int tid = threadIdx.x;
  const int lane = tid & 63;
  const int wave = tid >> 6;
  const int wr = wave >> 2, wc = wave & 3;  // 2x4 wave grid, each 128x64 of C

  // T1: XCD-aware block swizzle (grid % 8 == 0 by construction)
  const int nwg = gridDim.x;
  const int wg = blockIdx.x;
  const int wgs = (wg & 7) * (nwg >> 3) + (wg >> 3);
  const int nbn = N >> 8;
  const int m0 = (wgs / nbn) << 8;
  const int n0 = (wgs % nbn) << 8;
  const int NT = K >> 6;  // even for all our shapes (64, 160)

  const int lrow = lane & 15;
  const int kslot = lane >> 4;       // 0..3: 8-elem k-slot within 64-col row
  const int st_row = lane >> 3;      // staging: row within the 8-row stripe
  const int st_slot = lane & 7;
  const int st_src = ((st_slot ^ st_row) * 8);  // T2 inverse-swizzled source

  f32x4 acc[8][4] = {};

  auto stage = [&](const u16* __restrict__ G, int row0, u16* lds, int half,
                   int kt) {
#pragma unroll
    for (int r = 0; r < 2; ++r) {
      int row = half * 128 + r * 64 + wave * 8 + st_row;
      const u16* g = G + (long)(row0 + row) * K + kt * 64 + st_src;
      u16* l = lds + row * 64 + st_slot * 8;
      gload16(g, l);
    }
  };
  // T2 swizzled LDS fragment reads (2-way max bank aliasing = free)
  auto ldA = [&](const u16* sa, int mh, int m, int ks) -> bf16x8 {
    int row = wr * 128 + mh * 64 + m * 16 + lrow;
    int slot = (ks * 4 + kslot) ^ (row & 7);
    return *(const bf16x8*)(sa + row * 64 + slot * 8);
  };
  auto ldB = [&](const u16* sb, int n, int ks) -> bf16x8 {
    int row = wc * 64 + n * 16 + lrow;
    int slot = (ks * 4 + kslot) ^ (row & 7);
    return *(const bf16x8*)(sb + row * 64 + slot * 8);
  };

  bf16x8 aT[4][2];  // loop-carried: A rows mh0 of current tile

  // one K-tile: read-ahead schedule. b01 = tile-t B cols n01 (consumed Q1,Q4);
  // b01n = tile-(t+1) B cols n01 (written at P3b).
  auto ktile = [&](int t, const u16* sa, const u16* sb, u16* saN,
                   const u16* sbN, bf16x8 (&b01)[2][2],
                   bf16x8 (&b01n)[2][2]) {
    bf16x8 b23[2][2], aB[4][2];

    // ---- P1f: ds b23(t) | stage A0(t+1) | bar
#pragma unroll
    for (int n = 0; n < 2; ++n)
#pragma unroll
      for (int ks = 0; ks < 2; ++ks) b23[n][ks] = ldB(sb, n + 2, ks);
    if (t + 1 < NT) stage(A, m0, saN, 0, t + 1);
    __builtin_amdgcn_s_barrier();
    // ---- P1b: lgkm(4) drains b01(t),aT(t); Q1
    asm volatile("s_waitcnt lgkmcnt(4)");
    __builtin_amdgcn_sched_barrier(0);
    __builtin_amdgcn_s_setprio(1);
#pragma unroll
    for (int m = 0; m < 4; ++m)
#pragma unroll
      for (int n = 0; n < 2; ++n)
#pragma unroll
        for (int ks = 0; ks < 2; ++ks)
          acc[m][n] = __builtin_amdgcn_mfma_f32_16x16x32_bf16(
              aT[m][ks], b01[n][ks], acc[m][n], 0, 0, 0);
    __builtin_amdgcn_s_setprio(0);
    __builtin_amdgcn_s_barrier();

    // ---- P2f: ds aB(t) | stage A1(t+1) | bar
#pragma unroll
    for (int m = 0; m < 4; ++m)
#pragma unroll
      for (int ks = 0; ks < 2; ++ks) aB[m][ks] = ldA(sa, 1, m, ks);
    if (t + 1 < NT) stage(A, m0, saN, 1, t + 1);
    __builtin_amdgcn_s_barrier();
    // ---- P2b: lgkm(8) drains b23; Q2
    asm volatile("s_waitcnt lgkmcnt(8)");
    __builtin_amdgcn_sched_barrier(0);
    __builtin_amdgcn_s_setprio(1);
#pragma unroll
    for (int m = 0; m < 4; ++m)
#pragma unroll
      for (int n = 0; n < 2; ++n)
#pragma unroll
        for (int ks = 0; ks < 2; ++ks)
          acc[m][n + 2] = __builtin_amdgcn_mfma_f32_16x16x32_bf16(
              aT[m][ks], b23[n][ks], acc[m][n + 2], 0, 0, 0);
    __builtin_amdgcn_s_setprio(0);
    __builtin_amdgcn_s_barrier();

    // ---- P3f: stage B0(t+2) | vmcnt proves B(t+1) | bar
    if (t + 2 < NT) {
      stage(B, n0, (u16*)sb, 0, t + 2);
      asm volatile("s_waitcnt vmcnt(6)" ::: "memory");
    } else if (t + 1 < NT) {
      asm volatile("s_waitcnt vmcnt(4)" ::: "memory");
    }
    __builtin_amdgcn_s_barrier();
    // ---- P3b: lgkm(0) drains aB; read-ahead b01(t+1); Q3
    asm volatile("s_waitcnt lgkmcnt(0)");
    __builtin_amdgcn_sched_barrier(0);
    if (t + 1 < NT) {
#pragma unroll
      for (int n = 0; n < 2; ++n)
#pragma unroll
        for (int ks = 0; ks < 2; ++ks) b01n[n][ks] = ldB(sbN, n, ks);
    }
    __builtin_amdgcn_sched_barrier(0);
    __builtin_amdgcn_s_setprio(1);
#pragma unroll
    for (int m = 0; m < 4; ++m)
#pragma unroll
      for (int n = 0; n < 2; ++n)
#pragma unroll
        for (int ks = 0; ks < 2; ++ks)
          acc[4 + m][n + 2] = __builtin_amdgcn_mfma_f32_16x16x32_bf16(
              aB[m][ks], b23[n][ks], acc[4 + m][n + 2], 0, 0, 0);
    __builtin_amdgcn_s_setprio(0);
    __builtin_amdgcn_s_barrier();

    // ---- P4f: stage B1(t+2) | vmcnt proves A(t+1) | bar
    if (t + 2 < NT) {
      stage(B, n0, (u16*)sb, 1, t + 2);
      asm volatile("s_waitcnt vmcnt(4)" ::: "memory");
    } else if (t + 1 < NT) {
      asm volatile("s_waitcnt vmcnt(0)" ::: "memory");
    }
    __builtin_amdgcn_s_barrier();
    // ---- P4b: read-ahead aT(t+1); Q4 (operands already drained)
    __builtin_amdgcn_sched_barrier(0);
    if (t + 1 < NT) {
#pragma unroll
      for (int m = 0; m < 4; ++m)
#pragma unroll
        for (int ks = 0; ks < 2; ++ks) aT[m][ks] = ldA(saN, 0, m, ks);
    }
    __builtin_amdgcn_sched_barrier(0);
    __builtin_amdgcn_s_setprio(1);
#pragma unroll
    for (int m = 0; m < 4; ++m)
#pragma unroll
      for (int n = 0; n < 2; ++n)
#pragma unroll
        for (int ks = 0; ks < 2; ++ks)
          acc[4 + m][n] = __builtin_amdgcn_mfma_f32_16x16x32_bf16(
              aB[m][ks], b01[n][ks], acc[4 + m][n], 0, 0, 0);
    __builtin_amdgcn_s_setprio(0);
    __builtin_amdgcn_s_barrier();
  };

  // ---- prologue: A(0),B(0),B(1) staged; vmcnt(4) drains tile 0 (leaves
  //      B(1) 4 in flight = steady-state invariant); preload b01(0), aT(0)
  stage(A, m0, sAbuf[0], 0, 0);
  stage(A, m0, sAbuf[0], 1, 0);
  stage(B, n0, sBbuf[0], 0, 0);
  stage(B, n0, sBbuf[0], 1, 0);
  if (NT > 1) {
    stage(B, n0, sBbuf[1], 0, 1);
    stage(B, n0, sBbuf[1], 1, 1);
    asm volatile("s_waitcnt vmcnt(4)" ::: "memory");
  } else {
    asm volatile("s_waitcnt vmcnt(0)" ::: "memory");
  }
  __builtin_amdgcn_s_barrier();

  bf16x8 b01A[2][2], b01B[2][2];
#pragma unroll
  for (int n = 0; n < 2; ++n)
#pragma unroll
    for (int ks = 0; ks < 2; ++ks) b01A[n][ks] = ldB(sBbuf[0], n, ks);
#pragma unroll
  for (int m = 0; m < 4; ++m)
#pragma unroll
    for (int ks = 0; ks < 2; ++ks) aT[m][ks] = ldA(sAbuf[0], 0, m, ks);

  // ---- main loop: static 2-tile unroll, named buffers (NT is even)
  for (int t = 0; t < NT; t += 2) {
    ktile(t, sAbuf[0], sBbuf[0], sAbuf[1], sBbuf[1], b01A, b01B);
    ktile(t + 1, sAbuf[1], sBbuf[1], sAbuf[0], sBbuf[0], b01B, b01A);
  }

  // ---- epilogue: C/D layout col=lane&15, row=(lane>>4)*4+reg (m89-verified)
  const int rb = m0 + wr * 128 + (lane >> 4) * 4;
  const int cb = n0 + wc * 64 + lrow;
#pragma unroll
  for (int mf = 0; mf < 8; ++mf) {
#pragma unroll
    for (int r = 0; r < 4; ++r) {
      const long rowoff = (long)(rb + mf * 16 + r) * N + cb;
#pragma unroll
      for (int n = 0; n < 4; ++n) {
        if (OUT_BF16)
          ((u16*)Cv)[rowoff + n * 16] = f2bf(acc[mf][n][r]);
        else
          ((float*)Cv)[rowoff + n * 16] = acc[mf][n][r];
      }
    }
  }
}

// ---------------- in-place LayerNorm over rows of 4096 ----------------
__global__ __launch_bounds__(256) void k_layernorm(
    float* __restrict__ h, const float* __restrict__ gamma,
    const float* __restrict__ beta) {
  const int H = 4096;
  float* p = h + (long)blockIdx.x * H;
  int t = threadIdx.x;
  float4 v[4];
  float sum = 0.f, sq = 0.f;
#pragma unroll
  for (int i = 0; i < 4; ++i) {
    v[i] = ((const float4*)p)[i * 256 + t];
    sum += v[i].x + v[i].y + v[i].z + v[i].w;
    sq += v[i].x * v[i].x + v[i].y * v[i].y + v[i].z * v[i].z + v[i].w * v[i].w;
  }
#pragma unroll
  for (int off = 32; off > 0; off >>= 1) {
    sum += __shfl_down(sum, off, 64);
    sq += __shfl_down(sq, off, 64);
  }
  __shared__ float ss[4], sg[4];
  if ((t & 63) == 0) { ss[t >> 6] = sum; sg[t >> 6] = sq; }
  __syncthreads();
  sum = ss[0] + ss[1] + ss[2] + ss[3];
  sq = sg[0] + sg[1] + sg[2] + sg[3];
  float mu = sum * (1.0f / H);
  float var = sq * (1.0f / H) - mu * mu;
  float rs = rsqrtf(var + 1e-5f);
#pragma unroll
  for (int i = 0; i < 4; ++i) {
    float4 g = ((const float4*)gamma)[i * 256 + t];
    float4 b = ((const float4*)beta)[i * 256 + t];
    float4 o;
    o.x = (v[i].x - mu) * rs * g.x + b.x;
    o.y = (v[i].y - mu) * rs * g.y + b.y;
    o.z = (v[i].z - mu) * rs * g.z + b.z;
    o.w = (v[i].w - mu) * rs * g.w + b.w;
    ((float4*)p)[i * 256 + t] = o;
  }
}

extern "C" void kernel_launch(void* const* d_in, const int* in_sizes, int n_in,
                              void* d_out, int out_size, void* d_ws,
                              size_t ws_size, hipStream_t stream) {
  const float* x      = (const float*)d_in[0];
  const float* w_a    = (const float*)d_in[1];
  const float* s_a    = (const float*)d_in[2];
  const float* w_b    = (const float*)d_in[3];
  const float* s_b    = (const float*)d_in[4];
  const float* w_proj = (const float*)d_in[5];
  const float* gamma  = (const float*)d_in[6];
  const float* beta   = (const float*)d_in[7];

  const int H = 4096, LO = 8192, SO = 2048, NR = 8192;
  const int KT = LO + SO;  // 10240

  char* ws = (char*)d_ws;
  u16* xb   = (u16*)(ws);                 // 64 MiB
  u16* wpb  = (u16*)(ws + 0x4000000L);    // 80 MiB
  u16* wqT  = (u16*)(ws + 0x9000000L);    // 80 MiB
  u16* weff = (u16*)(ws + 0xE000000L);    // 32 MiB
  float* h  = (float*)d_out;

  // 1. convert w_proj; quantize+transpose weights (GEMM1 operands first)
  k_f32_to_bf16<<<2048, 256, 0, stream>>>(w_proj, wpb, (long)H * KT);
  k_quant_transpose<<<dim3(LO / 64, H / 64), 256, 0, stream>>>(
      w_a, s_a, wqT, LO, H, H / 128, (long)KT, 0);
  k_quant_transpose<<<dim3(SO / 64, H / 64), 256, 0, stream>>>(
      w_b, s_b, wqT, SO, H, H / 128, (long)KT, LO);

  // 2. W_eff = w_proj @ Wq  -> bf16 [H][H]
  k_gemm8<true><<<(H / 256) * (H / 256), 512, 0, stream>>>(
      wpb, wqT, (void*)weff, H, H, KT);

  // 3. convert x (after GEMM1 so xb is LLC-hot for GEMM2)
  k_f32_to_bf16<<<2048, 256, 0, stream>>>(x, xb, (long)NR * H);

  // 4. h = x @ W_eff^T  -> fp32 into d_out
  k_gemm8<false><<<(NR / 256) * (H / 256), 512, 0, stream>>>(
      xb, weff, (void*)h, NR, H, H);

  // 5. LayerNorm in place
  k_layernorm<<<NR, 256, 0, stream>>>(h, gamma, beta);
}

// Round 11
// 816.917 us; speedup vs baseline: 2.8562x; 2.8562x over previous
//
#include <hip/hip_runtime.h>

// ---------------------------------------------------------------------------
// TwoBranchFork: out = LN( concat(x@q(w_a)^T, x@q(w_b)^T) @ w_proj^T )
// Reassociated: W_eff = w_proj @ [q(w_a); q(w_b)]  (4096x4096), h = x @ W_eff^T
// Round 11: occupancy redesign — 2 blocks/CU for cross-block MFMA/LDS overlap.
//   block: 256x128 tile, BK=32, 512 threads (8 waves of 64x64), acc=64 AGPR,
//   LDS 48 KiB (A [128][64] + B [64][64] packed-pair, double-buffered)
//   -> 2 blocks/CU (96 KiB LDS, <=128 regs via __launch_bounds__(512,4)).
// Packed-pair LDS layout (BK=32): logical row r, k-slot u(0..3) stored at
//   [prow=r>>1][slot = (((r&1)<<2)|u) ^ (prow&7)] (8 slots of 16B per 128B
//   row). Conflict proof (8-lane service groups): lanes 0-7 of a frag read
//   cover prow j0..j0+3 x halves; j0%8==0 always (j0 = wr*32+m*8), so slots
//   = {p,p^4 : p=0..3} = all 8 -> 8 distinct bank groups, conflict-free.
// Per K-tile schedule (2 barriers):
//   [ds a4+b4 | lgkm(0)+schedbar | BAR | stage A(t+2)x2,B(t+2)x1 | schedbar |
//    setprio MFMA x16 | vmcnt(3|0) | BAR]
//   BAR1 after lgkm0: all waves' reads executed -> stages (same-parity bufs)
//   write-after-read safe. Stages issue before MFMA -> HBM latency hides
//   under MFMA. vmcnt(3) drains t-1's 3 stages -> A(t+1),B(t+1) proven before
//   BAR2 -> next tile's reads safe cross-wave. Steady invariant: 3 in flight.
//   Edges: t+2>=NT skip stages, vmcnt(0). Prologue: 6 stages, vmcnt(3).
// ---------------------------------------------------------------------------

typedef unsigned int u32;
typedef unsigned short u16;
typedef __bf16 bf16x8 __attribute__((ext_vector_type(8)));
typedef float f32x4 __attribute__((ext_vector_type(4)));
typedef u16 u16x8 __attribute__((ext_vector_type(8)));

#define AS1 __attribute__((address_space(1)))
#define AS3 __attribute__((address_space(3)))

__device__ __forceinline__ u16 f2bf(float f) {
  u32 u = __float_as_uint(f);
  u32 r = (u + 0x7fffu + ((u >> 16) & 1u)) >> 16;  // RNE
  return (u16)r;
}

// fp8 e4m3fn quantize-dequantize via HW cvt (OCP format + RNE on gfx950)
__device__ __forceinline__ float q_e4m3(float v) {
  int p = __builtin_amdgcn_cvt_pk_fp8_f32(v, v, 0, false);
  return __builtin_amdgcn_cvt_f32_fp8(p, 0);
}

__device__ __forceinline__ void gload16(const void* g, void* l) {
  __builtin_amdgcn_global_load_lds((const AS1 u32*)g, (AS3 u32*)l, 16, 0, 0);
}

// ---------------- elementwise f32 -> bf16 ----------------
__global__ __launch_bounds__(256) void k_f32_to_bf16(
    const float* __restrict__ in, u16* __restrict__ out, long n) {
  long i0 = ((long)blockIdx.x * 256 + threadIdx.x) * 8;
  long stride = (long)gridDim.x * 256 * 8;
  for (long i = i0; i < n; i += stride) {
    float4 a = *(const float4*)(in + i);
    float4 b = *(const float4*)(in + i + 4);
    u16x8 o;
    o[0] = f2bf(a.x); o[1] = f2bf(a.y); o[2] = f2bf(a.z); o[3] = f2bf(a.w);
    o[4] = f2bf(b.x); o[5] = f2bf(b.y); o[6] = f2bf(b.z); o[7] = f2bf(b.w);
    *(u16x8*)(out + i) = o;
  }
}

// ---------------- quantize (fp8 rt) + transpose into wqT ----------------
__global__ __launch_bounds__(256) void k_quant_transpose(
    const float* __restrict__ w, const float* __restrict__ s,
    u16* __restrict__ oT, int J, int Kd, int sCols, long oStride, int oColOff) {
  __shared__ u16 tile[64][72];
  int j0 = blockIdx.x * 64;
  int k0 = blockIdx.y * 64;
  float sc = s[(j0 >> 7) * sCols + (k0 >> 7)];
  int t = threadIdx.x;
  int row = t >> 2, seg = t & 3;
  const float4* src = (const float4*)(w + (long)(j0 + row) * Kd + k0 + seg * 16);
  u16* dst = &tile[row][seg * 16];
#pragma unroll
  for (int ii = 0; ii < 4; ++ii) {
    float4 v = src[ii];
    dst[ii * 4 + 0] = f2bf(q_e4m3(v.x / sc) * sc);
    dst[ii * 4 + 1] = f2bf(q_e4m3(v.y / sc) * sc);
    dst[ii * 4 + 2] = f2bf(q_e4m3(v.z / sc) * sc);
    dst[ii * 4 + 3] = f2bf(q_e4m3(v.w / sc) * sc);
  }
  __syncthreads();
  int r = t >> 2, cs = t & 3;
  u16* op = oT + (long)(k0 + r) * oStride + oColOff + j0 + cs * 16;
  u16x8 o0, o1;
#pragma unroll
  for (int ii = 0; ii < 8; ++ii) o0[ii] = tile[cs * 16 + ii][r];
#pragma unroll
  for (int ii = 0; ii < 8; ++ii) o1[ii] = tile[cs * 16 + 8 + ii][r];
  *(u16x8*)op = o0;
  *(u16x8*)(op + 8) = o1;
}

// ------- 256x128 / BK=32 bf16 bt-GEMM, 2 blocks/CU: C = A[M,K]*B[N,K]^T -----
template <bool OUT_BF16>
__global__ __launch_bounds__(512, 4) void k_gemm2b(
    const u16* __restrict__ A, const u16* __restrict__ B, void* __restrict__ Cv,
    int M, int N, int K) {
  __shared__ u16 sAbuf[2][128 * 64];  // packed-pair: 256 rows x 32 k
  __shared__ u16 sBbuf[2][64 * 64];   // packed-pair: 128 rows x 32 k

  const int tid = threadIdx.x;
  const int lane = tid & 63;
  const int wave = tid >> 6;
  const int wr = wave >> 1;  // 0..3 : 64-row block
  const int wc = wave & 1;   // 0..1 : 64-col block

  // T1: XCD-aware block swizzle (grid % 8 == 0 by construction)
  const int nwg = gridDim.x;
  const int wg = blockIdx.x;
  const int wgs = (wg & 7) * (nwg >> 3) + (wg >> 3);
  const int nbn = N >> 7;
  const int m0 = (wgs / nbn) << 8;
  const int n0 = (wgs % nbn) << 7;
  const int NT = K >> 5;  // even for all our shapes (320, 128)

  const int lrow = lane & 15;
  const int kslot = lane >> 4;  // 0..3: 8-elem k-slot within 32-col row

  f32x4 acc[4][4] = {};

  // staging: linear LDS dest (base + tid*16B), inverse-swizzled global source
  auto stageA = [&](u16* lds, int h, int kt) {
    int prow = h * 64 + (tid >> 3);
    int slot = tid & 7;
    int uns = slot ^ (prow & 7);
    int r = 2 * prow + (uns >> 2);
    const u16* g = A + (long)(m0 + r) * K + kt * 32 + (uns & 3) * 8;
    gload16(g, lds + prow * 64 + slot * 8);
  };
  auto stageB = [&](u16* lds, int kt) {
    int prow = tid >> 3;  // 0..63
    int slot = tid & 7;
    int uns = slot ^ (prow & 7);
    int r = 2 * prow + (uns >> 2);
    const u16* g = B + (long)(n0 + r) * K + kt * 32 + (uns & 3) * 8;
    gload16(g, lds + prow * 64 + slot * 8);
  };
  // swizzled fragment reads (conflict-free per 8-lane group, see header)
  auto ldA = [&](const u16* sa, int m) -> bf16x8 {
    int r = wr * 64 + m * 16 + lrow;
    int prow = r >> 1;
    int slot = (((r & 1) << 2) | kslot) ^ (prow & 7);
    return *(const bf16x8*)(sa + prow * 64 + slot * 8);
  };
  auto ldB = [&](const u16* sb, int n) -> bf16x8 {
    int r = wc * 64 + n * 16 + lrow;
    int prow = r >> 1;
    int slot = (((r & 1) << 2) | kslot) ^ (prow & 7);
    return *(const bf16x8*)(sb + prow * 64 + slot * 8);
  };

  // one K-tile: [ds8 | lgkm0 | BAR | stage(t+2) | MFMA16 | vmcnt | BAR]
  auto ktile = [&](int t, const u16* sa, const u16* sb, u16* saW, u16* sbW) {
    bf16x8 a[4], b[4];
#pragma unroll
    for (int m = 0; m < 4; ++m) a[m] = ldA(sa, m);
#pragma unroll
    for (int n = 0; n < 4; ++n) b[n] = ldB(sb, n);
    asm volatile("s_waitcnt lgkmcnt(0)" ::: "memory");
    __builtin_amdgcn_sched_barrier(0);
    __builtin_amdgcn_s_barrier();  // all waves' reads executed
    if (t + 2 < NT) {              // stage 2 tiles ahead into same-parity bufs
      stageA(saW, 0, t + 2);
      stageA(saW, 1, t + 2);
      stageB(sbW, t + 2);
    }
    __builtin_amdgcn_sched_barrier(0);
    __builtin_amdgcn_s_setprio(1);
#pragma unroll
    for (int m = 0; m < 4; ++m)
#pragma unroll
      for (int n = 0; n < 4; ++n)
        acc[m][n] = __builtin_amdgcn_mfma_f32_16x16x32_bf16(a[m], b[n],
                                                            acc[m][n], 0, 0, 0);
    __builtin_amdgcn_s_setprio(0);
    if (t + 2 < NT)
      asm volatile("s_waitcnt vmcnt(3)" ::: "memory");  // drain t-1's stages
    else
      asm volatile("s_waitcnt vmcnt(0)" ::: "memory");
    __builtin_amdgcn_s_barrier();  // t+1 operands proven resident, all waves
  };

  // ---- prologue: tiles 0 and 1 staged (3 calls each); vmcnt(3) drains tile0
  stageA(sAbuf[0], 0, 0);
  stageA(sAbuf[0], 1, 0);
  stageB(sBbuf[0], 0);
  if (NT > 1) {
    stageA(sAbuf[1], 0, 1);
    stageA(sAbuf[1], 1, 1);
    stageB(sBbuf[1], 1);
    asm volatile("s_waitcnt vmcnt(3)" ::: "memory");
  } else {
    asm volatile("s_waitcnt vmcnt(0)" ::: "memory");
  }
  __builtin_amdgcn_s_barrier();

  // ---- main loop: static 2-tile unroll, named buffers (NT is even)
  for (int t = 0; t < NT; t += 2) {
    ktile(t, sAbuf[0], sBbuf[0], sAbuf[0], sBbuf[0]);
    ktile(t + 1, sAbuf[1], sBbuf[1], sAbuf[1], sBbuf[1]);
  }

  // ---- epilogue: C/D layout col=lane&15, row=(lane>>4)*4+reg (m89-verified)
  const int rb = m0 + wr * 64 + (lane >> 4) * 4;
  const int cb = n0 + wc * 64 + lrow;
#pragma unroll
  for (int m = 0; m < 4; ++m) {
#pragma unroll
    for (int r = 0; r < 4; ++r) {
      const long rowoff = (long)(rb + m * 16 + r) * N + cb;
#pragma unroll
      for (int n = 0; n < 4; ++n) {
        if (OUT_BF16)
          ((u16*)Cv)[rowoff + n * 16] = f2bf(acc[m][n][r]);
        else
          ((float*)Cv)[rowoff + n * 16] = acc[m][n][r];
      }
    }
  }
}

// ---------------- in-place LayerNorm over rows of 4096 ----------------
__global__ __launch_bounds__(256) void k_layernorm(
    float* __restrict__ h, const float* __restrict__ gamma,
    const float* __restrict__ beta) {
  const int H = 4096;
  float* p = h + (long)blockIdx.x * H;
  int t = threadIdx.x;
  float4 v[4];
  float sum = 0.f, sq = 0.f;
#pragma unroll
  for (int i = 0; i < 4; ++i) {
    v[i] = ((const float4*)p)[i * 256 + t];
    sum += v[i].x + v[i].y + v[i].z + v[i].w;
    sq += v[i].x * v[i].x + v[i].y * v[i].y + v[i].z * v[i].z + v[i].w * v[i].w;
  }
#pragma unroll
  for (int off = 32; off > 0; off >>= 1) {
    sum += __shfl_down(sum, off, 64);
    sq += __shfl_down(sq, off, 64);
  }
  __shared__ float ss[4], sg[4];
  if ((t & 63) == 0) { ss[t >> 6] = sum; sg[t >> 6] = sq; }
  __syncthreads();
  sum = ss[0] + ss[1] + ss[2] + ss[3];
  sq = sg[0] + sg[1] + sg[2] + sg[3];
  float mu = sum * (1.0f / H);
  float var = sq * (1.0f / H) - mu * mu;
  float rs = rsqrtf(var + 1e-5f);
#pragma unroll
  for (int i = 0; i < 4; ++i) {
    float4 g = ((const float4*)gamma)[i * 256 + t];
    float4 b = ((const float4*)beta)[i * 256 + t];
    float4 o;
    o.x = (v[i].x - mu) * rs * g.x + b.x;
    o.y = (v[i].y - mu) * rs * g.y + b.y;
    o.z = (v[i].z - mu) * rs * g.z + b.z;
    o.w = (v[i].w - mu) * rs * g.w + b.w;
    ((float4*)p)[i * 256 + t] = o;
  }
}

extern "C" void kernel_launch(void* const* d_in, const int* in_sizes, int n_in,
                              void* d_out, int out_size, void* d_ws,
                              size_t ws_size, hipStream_t stream) {
  const float* x      = (const float*)d_in[0];
  const float* w_a    = (const float*)d_in[1];
  const float* s_a    = (const float*)d_in[2];
  const float* w_b    = (const float*)d_in[3];
  const float* s_b    = (const float*)d_in[4];
  const float* w_proj = (const float*)d_in[5];
  const float* gamma  = (const float*)d_in[6];
  const float* beta   = (const float*)d_in[7];

  const int H = 4096, LO = 8192, SO = 2048, NR = 8192;
  const int KT = LO + SO;  // 10240

  char* ws = (char*)d_ws;
  u16* xb   = (u16*)(ws);                 // 64 MiB
  u16* wpb  = (u16*)(ws + 0x4000000L);    // 80 MiB
  u16* wqT  = (u16*)(ws + 0x9000000L);    // 80 MiB
  u16* weff = (u16*)(ws + 0xE000000L);    // 32 MiB
  float* h  = (float*)d_out;

  // 1. convert w_proj; quantize+transpose weights (GEMM1 operands first)
  k_f32_to_bf16<<<2048, 256, 0, stream>>>(w_proj, wpb, (long)H * KT);
  k_quant_transpose<<<dim3(LO / 64, H / 64), 256, 0, stream>>>(
      w_a, s_a, wqT, LO, H, H / 128, (long)KT, 0);
  k_quant_transpose<<<dim3(SO / 64, H / 64), 256, 0, stream>>>(
      w_b, s_b, wqT, SO, H, H / 128, (long)KT, LO);

  // 2. W_eff = w_proj @ Wq  -> bf16 [H][H]   (grid 16x32 = 512)
  k_gemm2b<true><<<(H / 256) * (H / 128), 512, 0, stream>>>(
      wpb, wqT, (void*)weff, H, H, KT);

  // 3. convert x (after GEMM1 so xb is LLC-hot for GEMM2)
  k_f32_to_bf16<<<2048, 256, 0, stream>>>(x, xb, (long)NR * H);

  // 4. h = x @ W_eff^T  -> fp32 into d_out   (grid 32x32 = 1024)
  k_gemm2b<false><<<(NR / 256) * (H / 128), 512, 0, stream>>>(
      xb, weff, (void*)h, NR, H, H);

  // 5. LayerNorm in place
  k_layernorm<<<NR, 256, 0, stream>>>(h, gamma, beta);
}